// Round 2
// baseline (321.583 us; speedup 1.0000x reference)
//
#include <hip/hip_runtime.h>
#include <hip/hip_bf16.h>

typedef __hip_bfloat16 bf16;
typedef __attribute__((ext_vector_type(4))) float f32x4;
typedef __attribute__((ext_vector_type(8))) short s16x8;

#define N_TOK 4096   // B*S
#define Dm    512
#define Fm    2048
#define Em    8

__device__ __forceinline__ float bf2f(bf16 v) { return __bfloat162float(v); }
__device__ __forceinline__ bf16  f2bf(float f) { return __float2bfloat16(f); }

// async global->LDS, 16B per lane; LDS dest is wave-uniform base + lane*16
#define GL16(g, l)                                                              \
  __builtin_amdgcn_global_load_lds(                                             \
      (const __attribute__((address_space(1))) void*)(g),                       \
      (__attribute__((address_space(3))) void*)(l), 16, 0, 0)

// ---------------- fp32 -> bf16 flat convert ----------------------------------
__global__ void cvt_f32_bf16(const float* __restrict__ in, bf16* __restrict__ out, int n4) {
  int i = blockIdx.x * 256 + threadIdx.x;
  if (i >= n4) return;
  float4 v = reinterpret_cast<const float4*>(in)[i];
  bf16 tmp[4] = {f2bf(v.x), f2bf(v.y), f2bf(v.z), f2bf(v.w)};
  __builtin_memcpy(out + (size_t)i * 4, tmp, 8);
}

// ---------------- fp32 [R][C] -> bf16 [C][R] tiled transpose-convert ---------
__global__ void transpose_cvt(const float* __restrict__ in, bf16* __restrict__ out,
                              int R, int C, long inb, long outb) {
  in  += (long)blockIdx.z * inb;
  out += (long)blockIdx.z * outb;
  __shared__ float t[32][33];
  int tx = threadIdx.x & 31, ty = threadIdx.x >> 5;
  int c0 = blockIdx.x * 32, r0 = blockIdx.y * 32;
#pragma unroll
  for (int i = 0; i < 32; i += 8)
    t[ty + i][tx] = in[(long)(r0 + ty + i) * C + c0 + tx];
  __syncthreads();
#pragma unroll
  for (int i = 0; i < 32; i += 8)
    out[(long)(c0 + ty + i) * R + r0 + tx] = f2bf(t[tx][ty + i]);
}

// ============ 256x256 deep-pipelined bf16 GEMM (T1+T2+T3+T4+T5) =============
// C = A @ Bt^T (+bias[, relu]).  A:[M][K] lda, Bt:[N][K] ldb, C row-major ldc.
// 8 waves (2x4), wave tile 128x64, BK=32, 3 LDS K-tile buffers (96 KB),
// depth-2 prefetch -> steady-state s_waitcnt vmcnt(4); one raw barrier/K-tile.
// LDS chunk swizzle: [row][slot] holds global k-chunk slot^((row>>1)&3),
// applied on the global SOURCE of global_load_lds and on the ds_read address.
// MFMA operands swapped => lane's 4 acc values are n-contiguous (packed store).
template <bool RELU, bool OUT_BF16>
__global__ __launch_bounds__(512, 2) void gemm256(
    const bf16* __restrict__ A, const bf16* __restrict__ Bt, void* __restrict__ Cout,
    const float* __restrict__ bias, int K, int lda, int ldb, int ldc,
    long abs_, long bbs, long cbs, long biasbs, int gx, int gy) {
  extern __shared__ bf16 lds[];  // 3 * (8192 A + 8192 B) bf16 = 96 KB

  // ---- T1: XCD-aware bijective swizzle (gridDim.x % 8 == 0 by construction)
  int nwg = gridDim.x;
  int id  = blockIdx.x;
  int lid = (id & 7) * (nwg >> 3) + (id >> 3);
  int per = gx * gy;
  int e   = lid / per;
  int rem = lid - e * per;
  int bx  = rem % gx, by = rem / gx;
  int bm  = bx * 256, bn = by * 256;

  A    += (long)e * abs_;
  Bt   += (long)e * bbs;
  bias += (long)e * biasbs;
  long coff = (long)e * cbs;

  int tid  = threadIdx.x;
  int w    = tid >> 6, lane = tid & 63;
  int wm   = w >> 2, wn = w & 3;  // 2x4 wave grid, 128x64 per wave

  // staging constants (per-lane): row-in-chunk, swizzled global k-chunk
  int srow   = lane >> 2;
  int schunk = (lane & 3) ^ ((lane >> 3) & 3);

  const bf16* Ab = A + (long)bm * lda;
  const bf16* Bb = Bt + (long)bn * ldb;

  int nt = K >> 5;  // BK = 32

  auto issue = [&](int t) {
    int k0 = t << 5;
    bf16* buf = lds + (t % 3) * 16384;
#pragma unroll
    for (int j = 0; j < 2; ++j) {
      int ch   = j * 8 + w;                 // 1KB chunk index (16 rows)
      int rowA = ch * 16 + srow;
      GL16(Ab + (long)rowA * lda + k0 + schunk * 8, buf + ch * 512);
      GL16(Bb + (long)rowA * ldb + k0 + schunk * 8, buf + 8192 + ch * 512);
    }
  };

  f32x4 acc[8][4] = {};
  int la = lane & 15, q = lane >> 4;
  int slotr = q ^ ((la >> 1) & 3);  // ds_read swizzle (inverse of staging)

  auto compute = [&](int t) {
    const bf16* Abuf = lds + (t % 3) * 16384;
    const bf16* Bbuf = Abuf + 8192;
    s16x8 af[8], bfr[4];
#pragma unroll
    for (int m = 0; m < 8; ++m) {
      int r = wm * 128 + m * 16 + la;
      af[m] = *reinterpret_cast<const s16x8*>(Abuf + r * 32 + slotr * 8);
    }
#pragma unroll
    for (int n = 0; n < 4; ++n) {
      int r = wn * 64 + n * 16 + la;
      bfr[n] = *reinterpret_cast<const s16x8*>(Bbuf + r * 32 + slotr * 8);
    }
    __builtin_amdgcn_s_setprio(1);
#pragma unroll
    for (int m = 0; m < 8; ++m)
#pragma unroll
      for (int n = 0; n < 4; ++n)
        acc[m][n] = __builtin_amdgcn_mfma_f32_16x16x32_bf16(bfr[n], af[m], acc[m][n], 0, 0, 0);
    __builtin_amdgcn_s_setprio(0);
  };

  // prologue: tiles 0 and 1 in flight (8 loads/wave outstanding)
  issue(0);
  issue(1);

  for (int t = 0; t < nt - 1; ++t) {
    asm volatile("s_waitcnt vmcnt(4)" ::: "memory");  // tile t's 4 loads done
    __builtin_amdgcn_s_barrier();                     // all waves' loads visible
    asm volatile("" ::: "memory");
    __builtin_amdgcn_sched_barrier(0);
    if (t + 2 < nt) issue(t + 2);                     // overwrite buf[(t-1)%3]
    compute(t);
    __builtin_amdgcn_sched_barrier(0);
  }
  // tail tile: drain (only place vmcnt reaches 0)
  asm volatile("s_waitcnt vmcnt(0)" ::: "memory");
  __builtin_amdgcn_s_barrier();
  asm volatile("" ::: "memory");
  __builtin_amdgcn_sched_barrier(0);
  compute(nt - 1);

  // epilogue: lane holds C[bm + wm*128 + m*16 + la][bn + wn*64 + n*16 + q*4 + r]
  int nbase0 = bn + wn * 64 + q * 4;
#pragma unroll
  for (int m = 0; m < 8; ++m) {
    int gm = bm + wm * 128 + m * 16 + la;
#pragma unroll
    for (int n = 0; n < 4; ++n) {
      int gn = nbase0 + n * 16;
      float4 b4 = *reinterpret_cast<const float4*>(bias + gn);
      float v0 = acc[m][n][0] + b4.x, v1 = acc[m][n][1] + b4.y;
      float v2 = acc[m][n][2] + b4.z, v3 = acc[m][n][3] + b4.w;
      if (RELU) {
        v0 = fmaxf(v0, 0.f); v1 = fmaxf(v1, 0.f);
        v2 = fmaxf(v2, 0.f); v3 = fmaxf(v3, 0.f);
      }
      long idx = coff + (long)gm * ldc + gn;
      if (OUT_BF16) {
        bf16 tmp[4] = {f2bf(v0), f2bf(v1), f2bf(v2), f2bf(v3)};
        __builtin_memcpy((bf16*)Cout + idx, tmp, 8);
      } else {
        float tmp[4] = {v0, v1, v2, v3};
        __builtin_memcpy((float*)Cout + idx, tmp, 16);
      }
    }
  }
}

// ---------------- 128x128 bf16 MFMA GEMM (kept for the small N=512 GEMMs) ----
template <bool RELU, bool OUT_BF16>
__global__ __launch_bounds__(256, 2) void gemm_bt(
    const bf16* __restrict__ A, const bf16* __restrict__ Bt, void* __restrict__ Cout,
    const float* __restrict__ bias, int M, int N, int K, int lda, int ldb, int ldc,
    long abs_, long bbs, long cbs, long biasbs, const int* __restrict__ eid,
    int eid_scale) {
  int e = blockIdx.z;
  A    += (long)e * abs_;
  Bt   += (long)e * bbs;
  bias += (long)e * biasbs;
  long coff = (long)e * cbs;
  if (eid) A += (long)(*eid) * eid_scale;

  __shared__ bf16 As[128 * 32];
  __shared__ bf16 Bs[128 * 32];

  int tid = threadIdx.x;
  int wave = tid >> 6, lane = tid & 63;
  int wm = wave >> 1, wn = wave & 1;
  int bm = blockIdx.x * 128, bn = blockIdx.y * 128;

  int srow  = lane >> 2;
  int skoff = (lane & 3) * 8;

  f32x4 acc[4][4] = {};

  const bf16* Abase = A + (long)bm * lda;
  const bf16* Bbase = Bt + (long)bn * ldb;

  for (int k0 = 0; k0 < K; k0 += 32) {
    __syncthreads();
#pragma unroll
    for (int i = 0; i < 2; i++) {
      int r = wave * 32 + i * 16 + srow;
      GL16(Abase + (long)r * lda + k0 + skoff, As + (wave * 32 + i * 16) * 32);
      GL16(Bbase + (long)r * ldb + k0 + skoff, Bs + (wave * 32 + i * 16) * 32);
    }
    __syncthreads();

    s16x8 af[4], bfr[4];
#pragma unroll
    for (int m = 0; m < 4; m++)
      af[m] = *reinterpret_cast<const s16x8*>(As + (wm * 64 + m * 16 + (lane & 15)) * 32 +
                                              (lane >> 4) * 8);
#pragma unroll
    for (int n = 0; n < 4; n++)
      bfr[n] = *reinterpret_cast<const s16x8*>(Bs + (wn * 64 + n * 16 + (lane & 15)) * 32 +
                                               (lane >> 4) * 8);
#pragma unroll
    for (int m = 0; m < 4; m++)
#pragma unroll
      for (int n = 0; n < 4; n++)
        acc[m][n] = __builtin_amdgcn_mfma_f32_16x16x32_bf16(af[m], bfr[n], acc[m][n], 0, 0, 0);
  }

  int cr = (lane >> 4) * 4, cc = lane & 15;
#pragma unroll
  for (int m = 0; m < 4; m++) {
#pragma unroll
    for (int n = 0; n < 4; n++) {
      int col  = bn + wn * 64 + n * 16 + cc;
      float bv = bias ? bias[col] : 0.0f;
#pragma unroll
      for (int r = 0; r < 4; r++) {
        int row = bm + wm * 64 + m * 16 + cr + r;
        float v = acc[m][n][r] + bv;
        if (RELU) v = fmaxf(v, 0.0f);
        long idx = coff + (long)row * ldc + col;
        if (OUT_BF16)
          ((bf16*)Cout)[idx] = f2bf(v);
        else
          ((float*)Cout)[idx] = v;
      }
    }
  }
}

// ---------------- attention over the expert axis (E=8, H=8, HD=64) ----------
__global__ __launch_bounds__(256) void attn_kernel(const float* __restrict__ q,
                                                   const bf16* __restrict__ kv,
                                                   bf16* __restrict__ ctx,
                                                   const int* __restrict__ eid) {
  int wave = threadIdx.x >> 6, lane = threadIdx.x & 63;
  int n = blockIdx.x * 4 + wave;
  int h = lane >> 3, f = lane & 7;
  int e3 = *eid;
  const bf16* kvn = kv + (long)n * Em * (2 * Dm);
  const float* qh = q + (long)n * Dm + h * 64;
  const bf16* kf = kvn + f * (2 * Dm) + h * 64;
  float s = 0.f;
#pragma unroll
  for (int j = 0; j < 64; j++) s += qh[j] * bf2f(kf[j]);
  s *= 0.125f;
  s += (f <= e3) ? 1.0f : 0.0f;  // torch-faithful ADDITIVE float tril mask
  float mx = s;
#pragma unroll
  for (int d = 1; d < 8; d <<= 1) mx = fmaxf(mx, __shfl_xor(mx, d));
  float ex = expf(s - mx);
  float sm = ex;
#pragma unroll
  for (int d = 1; d < 8; d <<= 1) sm += __shfl_xor(sm, d);
  float at = ex / sm;
  int g = f;
  float acc[8] = {0, 0, 0, 0, 0, 0, 0, 0};
#pragma unroll
  for (int f2 = 0; f2 < 8; f2++) {
    float a = __shfl(at, (h << 3) | f2);
    const bf16* vf = kvn + f2 * (2 * Dm) + Dm + h * 64 + g * 8;
#pragma unroll
    for (int j = 0; j < 8; j++) acc[j] += a * bf2f(vf[j]);
  }
  bf16 tmp[8];
#pragma unroll
  for (int j = 0; j < 8; j++) tmp[j] = f2bf(acc[j]);
  __builtin_memcpy(ctx + (long)n * Dm + h * 64 + g * 8, tmp, 16);
}

extern "C" void kernel_launch(void* const* d_in, const int* in_sizes, int n_in,
                              void* d_out, int out_size, void* d_ws, size_t ws_size,
                              hipStream_t stream) {
  const float* x  = (const float*)d_in[0];
  const float* W1 = (const float*)d_in[1];
  const float* b1 = (const float*)d_in[2];
  const float* W2 = (const float*)d_in[3];
  const float* b2 = (const float*)d_in[4];
  const float* Wq = (const float*)d_in[5];
  const float* bq = (const float*)d_in[6];
  const float* Wk = (const float*)d_in[7];
  const float* bk = (const float*)d_in[8];
  const float* Wv = (const float*)d_in[9];
  const float* bv = (const float*)d_in[10];
  const float* Wo = (const float*)d_in[11];
  const float* bo = (const float*)d_in[12];
  const int* eid  = (const int*)d_in[13];

  char* w = (char*)d_ws;
  auto alloc = [&](size_t bytes) {
    char* p = w;
    w += (bytes + 255) & ~(size_t)255;
    return p;
  };
  bf16* xb   = (bf16*)alloc((size_t)N_TOK * Dm * 2);
  bf16* W1t  = (bf16*)alloc((size_t)Em * Fm * Dm * 2);
  bf16* W2t  = (bf16*)alloc((size_t)Em * Dm * Fm * 2);
  bf16* qw   = (bf16*)alloc((size_t)Dm * Dm * 2);
  bf16* kvw  = (bf16*)alloc((size_t)2 * Dm * Dm * 2);
  bf16* ow   = (bf16*)alloc((size_t)Dm * Dm * 2);
  float* bkv = (float*)alloc((size_t)2 * Dm * 4);
  bf16* hid  = (bf16*)alloc((size_t)Em * N_TOK * Fm * 2);   // 128 MB [e][n][f]
  bf16* eo   = (bf16*)alloc((size_t)N_TOK * Em * Dm * 2);   // [n][e][d]
  bf16* kv   = (bf16*)hid;                                  // alias: [n*E+e][2D]
  float* qb  = (float*)(hid + (size_t)N_TOK * Em * 2 * Dm);
  bf16* ctxb = (bf16*)(qb + (size_t)N_TOK * Dm);

  // allow 96 KB dynamic LDS on the big GEMM instantiations (idempotent)
  hipFuncSetAttribute(reinterpret_cast<const void*>(gemm256<true, true>),
                      hipFuncAttributeMaxDynamicSharedMemorySize, 98304);
  hipFuncSetAttribute(reinterpret_cast<const void*>(gemm256<false, true>),
                      hipFuncAttributeMaxDynamicSharedMemorySize, 98304);

  // ---- converts / transposes ----
  cvt_f32_bf16<<<(N_TOK * Dm / 4 + 255) / 256, 256, 0, stream>>>(x, xb, N_TOK * Dm / 4);
  transpose_cvt<<<dim3(Fm / 32, Dm / 32, Em), 256, 0, stream>>>(
      W1, W1t, Dm, Fm, (long)Dm * Fm, (long)Fm * Dm);
  transpose_cvt<<<dim3(Dm / 32, Fm / 32, Em), 256, 0, stream>>>(
      W2, W2t, Fm, Dm, (long)Fm * Dm, (long)Dm * Fm);
  int nw4 = Dm * Dm / 4;
  cvt_f32_bf16<<<(nw4 + 255) / 256, 256, 0, stream>>>(Wq, qw, nw4);
  cvt_f32_bf16<<<(nw4 + 255) / 256, 256, 0, stream>>>(Wk, kvw, nw4);
  cvt_f32_bf16<<<(nw4 + 255) / 256, 256, 0, stream>>>(Wv, kvw + (size_t)Dm * Dm, nw4);
  cvt_f32_bf16<<<(nw4 + 255) / 256, 256, 0, stream>>>(Wo, ow, nw4);
  hipMemcpyAsync(bkv, bk, Dm * sizeof(float), hipMemcpyDeviceToDevice, stream);
  hipMemcpyAsync(bkv + Dm, bv, Dm * sizeof(float), hipMemcpyDeviceToDevice, stream);

  // ---- FFN stage 1: hid[e] = relu(x @ W1[e] + b1[e])  M=4096 N=2048 K=512
  gemm256<true, true><<<16 * 8 * Em, 512, 98304, stream>>>(
      xb, W1t, hid, b1, Dm, Dm, Dm, Fm,
      0L, (long)Fm * Dm, (long)N_TOK * Fm, (long)Fm, 16, 8);
  // ---- FFN stage 2: eo[n][e][:] = hid[e] @ W2[e] + b2[e]  M=4096 N=512 K=2048
  gemm256<false, true><<<16 * 2 * Em, 512, 98304, stream>>>(
      hid, W2t, eo, b2, Fm, Fm, Fm, Em * Dm,
      (long)N_TOK * Fm, (long)Dm * Fm, (long)Dm, (long)Dm, 16, 2);
  // ---- K|V for all expert rows: M=32768 N=1024 K=512
  gemm256<false, true><<<128 * 4, 512, 98304, stream>>>(
      eo, kvw, kv, bkv, Dm, Dm, Dm, 2 * Dm,
      0L, 0L, 0L, 0L, 128, 4);
  // ---- Q only for expert row e_id (small: keep 128^2 kernel)
  gemm_bt<false, false><<<dim3(N_TOK / 128, Dm / 128, 1), 256, 0, stream>>>(
      eo, qw, qb, bq, N_TOK, Dm, Dm, Em * Dm, Dm, Dm,
      0L, 0L, 0L, 0L, eid, Dm);
  // ---- attention over experts ----
  attn_kernel<<<N_TOK / 4, 256, 0, stream>>>(qb, kv, ctxb, eid);
  // ---- out projection -> d_out (fp32) ----
  gemm_bt<false, false><<<dim3(N_TOK / 128, Dm / 128, 1), 256, 0, stream>>>(
      ctxb, ow, (float*)d_out, bo, N_TOK, Dm, Dm, Dm, Dm, Dm,
      0L, 0L, 0L, 0L, nullptr, 0);
}

// Round 8
// 316.674 us; speedup vs baseline: 1.0155x; 1.0155x over previous
//
#include <hip/hip_runtime.h>
#include <hip/hip_bf16.h>

typedef __hip_bfloat16 bf16;
typedef __attribute__((ext_vector_type(4))) float f32x4;
typedef __attribute__((ext_vector_type(8))) short s16x8;

#define N_TOK 4096   // B*S
#define Dm    512
#define Fm    2048
#define Em    8

__device__ __forceinline__ float bf2f(bf16 v) { return __bfloat162float(v); }
__device__ __forceinline__ bf16  f2bf(float f) { return __float2bfloat16(f); }

// async global->LDS, 16B per lane; LDS dest is wave-uniform base + lane*16
#define GL16(g, l)                                                              \
  __builtin_amdgcn_global_load_lds(                                             \
      (const __attribute__((address_space(1))) void*)(g),                       \
      (__attribute__((address_space(3))) void*)(l), 16, 0, 0)

#define BAR()                                   \
  do {                                          \
    __builtin_amdgcn_s_barrier();               \
    asm volatile("" ::: "memory");              \
  } while (0)

// ---------------- fp32 -> bf16 flat convert ----------------------------------
__global__ void cvt_f32_bf16(const float* __restrict__ in, bf16* __restrict__ out, int n4) {
  int i = blockIdx.x * 256 + threadIdx.x;
  if (i >= n4) return;
  float4 v = reinterpret_cast<const float4*>(in)[i];
  bf16 tmp[4] = {f2bf(v.x), f2bf(v.y), f2bf(v.z), f2bf(v.w)};
  __builtin_memcpy(out + (size_t)i * 4, tmp, 8);
}

// ---------------- fp32 [R][C] -> bf16 [C][R] tiled transpose-convert ---------
__global__ void transpose_cvt(const float* __restrict__ in, bf16* __restrict__ out,
                              int R, int C, long inb, long outb) {
  in  += (long)blockIdx.z * inb;
  out += (long)blockIdx.z * outb;
  __shared__ float t[32][33];
  int tx = threadIdx.x & 31, ty = threadIdx.x >> 5;
  int c0 = blockIdx.x * 32, r0 = blockIdx.y * 32;
#pragma unroll
  for (int i = 0; i < 32; i += 8)
    t[ty + i][tx] = in[(long)(r0 + ty + i) * C + c0 + tx];
  __syncthreads();
#pragma unroll
  for (int i = 0; i < 32; i += 8)
    out[(long)(c0 + ty + i) * R + r0 + tx] = f2bf(t[tx][ty + i]);
}

// ======== 256x256 8-phase deep-pipelined bf16 GEMM (T1+T2+T3+T4+T5) =========
// C = A @ Bt^T (+bias[, relu]).  A:[M][K] lda, Bt:[N][K] ldb, C row-major ldc.
// BK=64, 8 waves (2Mx4N), 2 LDS tile buffers (128 KB).
// RACE FIX (r8): wave footprint is SPLIT across tile halves -- wave owns
// A-rows {wm*64..+63} U {128+wm*64..+63}, B-rows {wn*32..+31} U {128+wn*32..+31}
// so quadrant (mh,nh) touches exactly half mh of A / half nh of B for EVERY
// wave. Wait chain per K-tile (verified per-wave):
//   t start: outstanding {B(t)h1,A(t)h1}; h0 halves retired by prev ph4 vmcnt(4)
//   ph1 reads h0/h0, stages A(t+1)h0, vmcnt(4) retires B(t)h1
//   ph2 reads B-h1,  stages B(t+1)h0, vmcnt(4) retires A(t)h1
//   ph3 reads A-h1,  stages B(t+1)h1 (no wait)
//   ph4 (h1/h1),     stages A(t+1)h1, vmcnt(4) retires A/B(t+1)h0
// vmcnt never 0 except final-tile drain (2 -> 0). Chunk-XOR swizzle
// (slot ^= row&7) on staged SOURCE and on ds_read address.
template <bool RELU, bool OUT_BF16>
__global__ __launch_bounds__(512, 2) void gemm8(
    const bf16* __restrict__ A, const bf16* __restrict__ Bt, void* __restrict__ Cout,
    const float* __restrict__ bias, int K, int lda, int ldb, int ldc,
    long abs_, long bbs, long cbs, long biasbs, int gx, int gy) {
  extern __shared__ bf16 lds[];  // 2 * (16384 A + 16384 B) bf16 = 128 KB

  // ---- T1: XCD-aware bijective swizzle (gridDim.x % 8 == 0 by construction)
  int nwg = gridDim.x;
  int id  = blockIdx.x;
  int lid = (id & 7) * (nwg >> 3) + (id >> 3);
  int per = gx * gy;
  int e   = lid / per;
  int rem = lid - e * per;
  int bx  = rem % gx, by = rem / gx;
  int bm  = bx * 256, bn = by * 256;

  A    += (long)e * abs_;
  Bt   += (long)e * bbs;
  bias += (long)e * biasbs;
  long coff = (long)e * cbs;

  int tid  = threadIdx.x;
  int wv   = tid >> 6, lane = tid & 63;
  int wm   = wv >> 2, wn = wv & 3;  // 2x4 wave grid

  const bf16* Ab = A + (long)bm * lda;
  const bf16* Bb = Bt + (long)bn * ldb;

  int nt = K >> 6;  // BK = 64

  // ---- staging: one half-tile (128 rows x 64 cols of A or B) = 2 loads/thread
  auto stageHalf = [&](int t, int isB, int h) {
    if (t >= nt) return;
    int k0 = t << 6;
    bf16* base = lds + (t & 1) * 32768 + isB * 16384 + h * 8192;
    const bf16* src = isB ? Bb : Ab;
    int ldx = isB ? ldb : lda;
#pragma unroll
    for (int j = 0; j < 2; ++j) {
      int Ll = j * 512 + wv * 64 + lane;      // linear 16B-chunk index in half
      int gr = h * 128 + (Ll >> 3);           // global row within tile
      int c  = (Ll & 7) ^ (gr & 7);           // pre-swizzled source chunk
      GL16(src + (long)gr * ldx + k0 + c * 8, base + (j * 512 + wv * 64) * 8);
    }
  };

  f32x4 acc[8][4] = {};
  int la = lane & 15, q = lane >> 4;
  int sl0 = q ^ (la & 7);  // ds_read slot for kk=0; kk=1 slot = sl0 ^ 4

  // A rows for quadrant mh: mh*128 + wm*64 + mi*16 + la   (all within half mh)
  auto readA = [&](s16x8 af[4][2], int t, int mh) {
    const bf16* Abuf = lds + (t & 1) * 32768;
#pragma unroll
    for (int mi = 0; mi < 4; ++mi) {
      int r = mh * 128 + wm * 64 + mi * 16 + la;
#pragma unroll
      for (int kk = 0; kk < 2; ++kk)
        af[mi][kk] = *reinterpret_cast<const s16x8*>(Abuf + r * 64 + (sl0 ^ (kk * 4)) * 8);
    }
  };
  // B rows for quadrant nh: nh*128 + wn*32 + ni*16 + la   (all within half nh)
  auto readB = [&](s16x8 bfv[2][2], int t, int nh) {
    const bf16* Bbuf = lds + (t & 1) * 32768 + 16384;
#pragma unroll
    for (int ni = 0; ni < 2; ++ni) {
      int r = nh * 128 + wn * 32 + ni * 16 + la;
#pragma unroll
      for (int kk = 0; kk < 2; ++kk)
        bfv[ni][kk] = *reinterpret_cast<const s16x8*>(Bbuf + r * 64 + (sl0 ^ (kk * 4)) * 8);
    }
  };
  auto mfmaQ = [&](int mh, int nh, s16x8 af[4][2], s16x8 bfv[2][2]) {
    __builtin_amdgcn_s_setprio(1);
#pragma unroll
    for (int mi = 0; mi < 4; ++mi)
#pragma unroll
      for (int ni = 0; ni < 2; ++ni)
#pragma unroll
        for (int kk = 0; kk < 2; ++kk)
          acc[mh * 4 + mi][nh * 2 + ni] = __builtin_amdgcn_mfma_f32_16x16x32_bf16(
              bfv[ni][kk], af[mi][kk], acc[mh * 4 + mi][nh * 2 + ni], 0, 0, 0);
    __builtin_amdgcn_s_setprio(0);
  };

  // ---- prologue: stage tile 0 in steady-state retire order A0,B0,B1,A1
  stageHalf(0, 0, 0);
  stageHalf(0, 1, 0);
  stageHalf(0, 1, 1);
  stageHalf(0, 0, 1);
  asm volatile("s_waitcnt vmcnt(4)" ::: "memory");  // A-h0,B-h0 of tile 0 landed
  BAR();

  s16x8 af[4][2], b0[2][2], b1[2][2];
  for (int t = 0; t < nt; ++t) {
    bool pf = (t + 1 < nt);
    // ---- phase 1: quadrant (0,0) -- needs A-h0,B-h0 (guaranteed at entry)
    readA(af, t, 0);
    readB(b0, t, 0);
    stageHalf(t + 1, 0, 0);
    if (pf) asm volatile("s_waitcnt vmcnt(4)" ::: "memory");  // retires B(t)h1
    else    asm volatile("s_waitcnt vmcnt(2)" ::: "memory");
    BAR();
    mfmaQ(0, 0, af, b0);
    BAR();
    // ---- phase 2: quadrant (0,1) -- needs B-h1 (just retired)
    readB(b1, t, 1);
    stageHalf(t + 1, 1, 0);
    if (pf) asm volatile("s_waitcnt vmcnt(4)" ::: "memory");  // retires A(t)h1
    else    asm volatile("s_waitcnt vmcnt(0)" ::: "memory");
    BAR();
    mfmaQ(0, 1, af, b1);
    BAR();
    // ---- phase 3: quadrant (1,0) -- needs A-h1 (just retired)
    readA(af, t, 1);
    stageHalf(t + 1, 1, 1);
    BAR();
    mfmaQ(1, 0, af, b0);
    BAR();
    // ---- phase 4: quadrant (1,1); stage A1(t+1); retire A/B(t+1)h0
    stageHalf(t + 1, 0, 1);
    if (pf) asm volatile("s_waitcnt vmcnt(4)" ::: "memory");
    BAR();
    mfmaQ(1, 1, af, b1);
    BAR();
  }

  // epilogue: acc[m][n] -> C[bm + (m>>2)*128 + wm*64 + (m&3)*16 + la]
  //                        [bn + (n>>1)*128 + wn*32 + (n&1)*16 + q*4 + r]
#pragma unroll
  for (int m = 0; m < 8; ++m) {
    int gm = bm + (m >> 2) * 128 + wm * 64 + (m & 3) * 16 + la;
#pragma unroll
    for (int n = 0; n < 4; ++n) {
      int gn = bn + (n >> 1) * 128 + wn * 32 + (n & 1) * 16 + q * 4;
      float4 b4 = *reinterpret_cast<const float4*>(bias + gn);
      float v0 = acc[m][n][0] + b4.x, v1 = acc[m][n][1] + b4.y;
      float v2 = acc[m][n][2] + b4.z, v3 = acc[m][n][3] + b4.w;
      if (RELU) {
        v0 = fmaxf(v0, 0.f); v1 = fmaxf(v1, 0.f);
        v2 = fmaxf(v2, 0.f); v3 = fmaxf(v3, 0.f);
      }
      long idx = coff + (long)gm * ldc + gn;
      if (OUT_BF16) {
        bf16 tmp[4] = {f2bf(v0), f2bf(v1), f2bf(v2), f2bf(v3)};
        __builtin_memcpy((bf16*)Cout + idx, tmp, 8);
      } else {
        float tmp[4] = {v0, v1, v2, v3};
        __builtin_memcpy((float*)Cout + idx, tmp, 16);
      }
    }
  }
}

// ---------------- 128x128 bf16 MFMA GEMM (small N=512 GEMMs: Q, out-proj) ----
template <bool RELU, bool OUT_BF16>
__global__ __launch_bounds__(256, 2) void gemm_bt(
    const bf16* __restrict__ A, const bf16* __restrict__ Bt, void* __restrict__ Cout,
    const float* __restrict__ bias, int M, int N, int K, int lda, int ldb, int ldc,
    long abs_, long bbs, long cbs, long biasbs, const int* __restrict__ eid,
    int eid_scale) {
  int e = blockIdx.z;
  A    += (long)e * abs_;
  Bt   += (long)e * bbs;
  bias += (long)e * biasbs;
  long coff = (long)e * cbs;
  if (eid) A += (long)(*eid) * eid_scale;

  __shared__ bf16 As[128 * 32];
  __shared__ bf16 Bs[128 * 32];

  int tid = threadIdx.x;
  int wave = tid >> 6, lane = tid & 63;
  int wm = wave >> 1, wn = wave & 1;
  int bm = blockIdx.x * 128, bn = blockIdx.y * 128;

  int srow  = lane >> 2;
  int skoff = (lane & 3) * 8;

  f32x4 acc[4][4] = {};

  const bf16* Abase = A + (long)bm * lda;
  const bf16* Bbase = Bt + (long)bn * ldb;

  for (int k0 = 0; k0 < K; k0 += 32) {
    __syncthreads();
#pragma unroll
    for (int i = 0; i < 2; i++) {
      int r = wave * 32 + i * 16 + srow;
      GL16(Abase + (long)r * lda + k0 + skoff, As + (wave * 32 + i * 16) * 32);
      GL16(Bbase + (long)r * ldb + k0 + skoff, Bs + (wave * 32 + i * 16) * 32);
    }
    __syncthreads();

    s16x8 af[4], bfr[4];
#pragma unroll
    for (int m = 0; m < 4; m++)
      af[m] = *reinterpret_cast<const s16x8*>(As + (wm * 64 + m * 16 + (lane & 15)) * 32 +
                                              (lane >> 4) * 8);
#pragma unroll
    for (int n = 0; n < 4; n++)
      bfr[n] = *reinterpret_cast<const s16x8*>(Bs + (wn * 64 + n * 16 + (lane & 15)) * 32 +
                                               (lane >> 4) * 8);
#pragma unroll
    for (int m = 0; m < 4; m++)
#pragma unroll
      for (int n = 0; n < 4; n++)
        acc[m][n] = __builtin_amdgcn_mfma_f32_16x16x32_bf16(af[m], bfr[n], acc[m][n], 0, 0, 0);
  }

  int cr = (lane >> 4) * 4, cc = lane & 15;
#pragma unroll
  for (int m = 0; m < 4; m++) {
#pragma unroll
    for (int n = 0; n < 4; n++) {
      int col  = bn + wn * 64 + n * 16 + cc;
      float bv = bias ? bias[col] : 0.0f;
#pragma unroll
      for (int r = 0; r < 4; r++) {
        int row = bm + wm * 64 + m * 16 + cr + r;
        float v = acc[m][n][r] + bv;
        if (RELU) v = fmaxf(v, 0.0f);
        long idx = coff + (long)row * ldc + col;
        if (OUT_BF16)
          ((bf16*)Cout)[idx] = f2bf(v);
        else
          ((float*)Cout)[idx] = v;
      }
    }
  }
}

// ---------------- attention over the expert axis (E=8, H=8, HD=64) ----------
__global__ __launch_bounds__(256) void attn_kernel(const float* __restrict__ q,
                                                   const bf16* __restrict__ kv,
                                                   bf16* __restrict__ ctx,
                                                   const int* __restrict__ eid) {
  int wave = threadIdx.x >> 6, lane = threadIdx.x & 63;
  int n = blockIdx.x * 4 + wave;
  int h = lane >> 3, f = lane & 7;
  int e3 = *eid;
  const bf16* kvn = kv + (long)n * Em * (2 * Dm);
  const float* qh = q + (long)n * Dm + h * 64;
  const bf16* kf = kvn + f * (2 * Dm) + h * 64;
  float s = 0.f;
#pragma unroll
  for (int j = 0; j < 64; j++) s += qh[j] * bf2f(kf[j]);
  s *= 0.125f;
  s += (f <= e3) ? 1.0f : 0.0f;  // torch-faithful ADDITIVE float tril mask
  float mx = s;
#pragma unroll
  for (int d = 1; d < 8; d <<= 1) mx = fmaxf(mx, __shfl_xor(mx, d));
  float ex = expf(s - mx);
  float sm = ex;
#pragma unroll
  for (int d = 1; d < 8; d <<= 1) sm += __shfl_xor(sm, d);
  float at = ex / sm;
  int g = f;
  float acc[8] = {0, 0, 0, 0, 0, 0, 0, 0};
#pragma unroll
  for (int f2 = 0; f2 < 8; f2++) {
    float a = __shfl(at, (h << 3) | f2);
    const bf16* vf = kvn + f2 * (2 * Dm) + Dm + h * 64 + g * 8;
#pragma unroll
    for (int j = 0; j < 8; j++) acc[j] += a * bf2f(vf[j]);
  }
  bf16 tmp[8];
#pragma unroll
  for (int j = 0; j < 8; j++) tmp[j] = f2bf(acc[j]);
  __builtin_memcpy(ctx + (long)n * Dm + h * 64 + g * 8, tmp, 16);
}

extern "C" void kernel_launch(void* const* d_in, const int* in_sizes, int n_in,
                              void* d_out, int out_size, void* d_ws, size_t ws_size,
                              hipStream_t stream) {
  const float* x  = (const float*)d_in[0];
  const float* W1 = (const float*)d_in[1];
  const float* b1 = (const float*)d_in[2];
  const float* W2 = (const float*)d_in[3];
  const float* b2 = (const float*)d_in[4];
  const float* Wq = (const float*)d_in[5];
  const float* bq = (const float*)d_in[6];
  const float* Wk = (const float*)d_in[7];
  const float* bk = (const float*)d_in[8];
  const float* Wv = (const float*)d_in[9];
  const float* bv = (const float*)d_in[10];
  const float* Wo = (const float*)d_in[11];
  const float* bo = (const float*)d_in[12];
  const int* eid  = (const int*)d_in[13];

  char* w = (char*)d_ws;
  auto alloc = [&](size_t bytes) {
    char* p = w;
    w += (bytes + 255) & ~(size_t)255;
    return p;
  };
  bf16* xb   = (bf16*)alloc((size_t)N_TOK * Dm * 2);
  bf16* W1t  = (bf16*)alloc((size_t)Em * Fm * Dm * 2);
  bf16* W2t  = (bf16*)alloc((size_t)Em * Dm * Fm * 2);
  bf16* qw   = (bf16*)alloc((size_t)Dm * Dm * 2);
  bf16* kvw  = (bf16*)alloc((size_t)2 * Dm * Dm * 2);
  bf16* ow   = (bf16*)alloc((size_t)Dm * Dm * 2);
  float* bkv = (float*)alloc((size_t)2 * Dm * 4);
  bf16* hid  = (bf16*)alloc((size_t)Em * N_TOK * Fm * 2);   // 128 MB [e][n][f]
  bf16* eo   = (bf16*)alloc((size_t)N_TOK * Em * Dm * 2);   // [n][e][d]
  bf16* kv   = (bf16*)hid;                                  // alias: [n*E+e][2D]
  float* qb  = (float*)(hid + (size_t)N_TOK * Em * 2 * Dm);
  bf16* ctxb = (bf16*)(qb + (size_t)N_TOK * Dm);

  // allow 128 KB dynamic LDS on the big GEMM instantiations
  hipFuncSetAttribute(reinterpret_cast<const void*>(gemm8<true, true>),
                      hipFuncAttributeMaxDynamicSharedMemorySize, 131072);
  hipFuncSetAttribute(reinterpret_cast<const void*>(gemm8<false, true>),
                      hipFuncAttributeMaxDynamicSharedMemorySize, 131072);

  // ---- converts / transposes ----
  cvt_f32_bf16<<<(N_TOK * Dm / 4 + 255) / 256, 256, 0, stream>>>(x, xb, N_TOK * Dm / 4);
  transpose_cvt<<<dim3(Fm / 32, Dm / 32, Em), 256, 0, stream>>>(
      W1, W1t, Dm, Fm, (long)Dm * Fm, (long)Fm * Dm);
  transpose_cvt<<<dim3(Dm / 32, Fm / 32, Em), 256, 0, stream>>>(
      W2, W2t, Fm, Dm, (long)Fm * Dm, (long)Dm * Fm);
  int nw4 = Dm * Dm / 4;
  cvt_f32_bf16<<<(nw4 + 255) / 256, 256, 0, stream>>>(Wq, qw, nw4);
  cvt_f32_bf16<<<(nw4 + 255) / 256, 256, 0, stream>>>(Wk, kvw, nw4);
  cvt_f32_bf16<<<(nw4 + 255) / 256, 256, 0, stream>>>(Wv, kvw + (size_t)Dm * Dm, nw4);
  cvt_f32_bf16<<<(nw4 + 255) / 256, 256, 0, stream>>>(Wo, ow, nw4);
  hipMemcpyAsync(bkv, bk, Dm * sizeof(float), hipMemcpyDeviceToDevice, stream);
  hipMemcpyAsync(bkv + Dm, bv, Dm * sizeof(float), hipMemcpyDeviceToDevice, stream);

  // ---- FFN stage 1: hid[e] = relu(x @ W1[e] + b1[e])  M=4096 N=2048 K=512
  gemm8<true, true><<<16 * 8 * Em, 512, 131072, stream>>>(
      xb, W1t, hid, b1, Dm, Dm, Dm, Fm,
      0L, (long)Fm * Dm, (long)N_TOK * Fm, (long)Fm, 16, 8);
  // ---- FFN stage 2: eo[n][e][:] = hid[e] @ W2[e] + b2[e]  M=4096 N=512 K=2048
  gemm8<false, true><<<16 * 2 * Em, 512, 131072, stream>>>(
      hid, W2t, eo, b2, Fm, Fm, Fm, Em * Dm,
      (long)N_TOK * Fm, (long)Dm * Fm, (long)Dm, (long)Dm, 16, 2);
  // ---- K|V for all expert rows: M=32768 N=1024 K=512
  gemm8<false, true><<<128 * 4, 512, 131072, stream>>>(
      eo, kvw, kv, bkv, Dm, Dm, Dm, 2 * Dm,
      0L, 0L, 0L, 0L, 128, 4);
  // ---- Q only for expert row e_id (small: keep 128^2 kernel)
  gemm_bt<false, false><<<dim3(N_TOK / 128, Dm / 128, 1), 256, 0, stream>>>(
      eo, qw, qb, bq, N_TOK, Dm, Dm, Em * Dm, Dm, Dm,
      0L, 0L, 0L, 0L, eid, Dm);
  // ---- attention over experts ----
  attn_kernel<<<N_TOK / 4, 256, 0, stream>>>(qb, kv, ctxb, eid);
  // ---- out projection -> d_out (fp32) ----
  gemm_bt<false, false><<<dim3(N_TOK / 128, Dm / 128, 1), 256, 0, stream>>>(
      ctxb, ow, (float*)d_out, bo, N_TOK, Dm, Dm, Dm, Dm, Dm,
      0L, 0L, 0L, 0L, nullptr, 0);
}